// Round 1
// baseline (155.796 us; speedup 1.0000x reference)
//
#include <hip/hip_runtime.h>

typedef __attribute__((ext_vector_type(8))) __bf16 bf16x8;
typedef __attribute__((ext_vector_type(4))) __bf16 bf16x4;
typedef __attribute__((ext_vector_type(4))) float f32x4;

#define D_OUT 4096
#define D_IN  4096
#define RANK  512
#define MROWS 8192   // BATCH*SEQ = 4*2048

__device__ __forceinline__ void gload_lds16(const void* gsrc, void* ldst) {
  __builtin_amdgcn_global_load_lds(
      (const __attribute__((address_space(1))) void*)gsrc,
      (__attribute__((address_space(3))) void*)ldst, 16, 0, 0);
}

// ---------------- f32 -> bf16 elementwise convert ----------------
__global__ __launch_bounds__(256) void cvt_f32_bf16(const float* __restrict__ in,
                                                    __bf16* __restrict__ out,
                                                    size_t n) {
  size_t i = ((size_t)blockIdx.x * 256 + threadIdx.x) * 4;
  size_t stride = (size_t)gridDim.x * 256 * 4;
  for (; i < n; i += stride) {
    float4 v = *(const float4*)(in + i);
    bf16x4 o = {(__bf16)v.x, (__bf16)v.y, (__bf16)v.z, (__bf16)v.w};
    *(bf16x4*)(out + i) = o;
  }
}

// ------------- f32 [R][C] -> bf16 [C][R] transpose-convert -------------
__global__ __launch_bounds__(256) void transpose_cvt(const float* __restrict__ in,
                                                     __bf16* __restrict__ out,
                                                     int R, int C) {
  __shared__ __bf16 tile[64][72];  // +8 pad
  const int r0 = blockIdx.x * 64, c0 = blockIdx.y * 64;
  const int t = threadIdx.x;
  const int tr = t / 16, tc4 = (t % 16) * 4;
#pragma unroll
  for (int i = 0; i < 4; ++i) {
    int r = i * 16 + tr;
    float4 v = *(const float4*)(in + (size_t)(r0 + r) * C + c0 + tc4);
    tile[r][tc4 + 0] = (__bf16)v.x;
    tile[r][tc4 + 1] = (__bf16)v.y;
    tile[r][tc4 + 2] = (__bf16)v.z;
    tile[r][tc4 + 3] = (__bf16)v.w;
  }
  __syncthreads();
#pragma unroll
  for (int i = 0; i < 4; ++i) {
    int c = i * 16 + tr;  // output row (n)
    bf16x4 o = {tile[tc4 + 0][c], tile[tc4 + 1][c], tile[tc4 + 2][c], tile[tc4 + 3][c]};
    *(bf16x4*)(out + (size_t)(c0 + c) * R + r0 + tc4) = o;
  }
}

// ------------- GEMM: C[M,N] = Amat[M,K] @ Bmat[N,K]^T (+bias) -------------
// bf16 inputs, f32 accumulate. 4 waves as 2x2. XOR-swizzled LDS,
// global_load_lds width-16 staging (linear LDS dest, inverse-swizzled source).
template <int BM, int BN, int BK, bool OUT_F32, bool BIAS>
__global__ __launch_bounds__(256) void gemm_bt(const __bf16* __restrict__ Amat,
                                               const __bf16* __restrict__ Bmat,
                                               const float* __restrict__ bias,
                                               void* __restrict__ Cout,
                                               int M, int N, int K) {
  constexpr int WM = BM / 2, WN = BN / 2;
  constexpr int MI = WM / 16, NI = WN / 16;
  __shared__ alignas(16) __bf16 Al[BM * BK];
  __shared__ alignas(16) __bf16 Bl[BN * BK];

  const int tid = threadIdx.x;
  const int wid = tid >> 6;
  const int lane = tid & 63;
  const int l15 = lane & 15, lhi = lane >> 4;
  const int wr = wid >> 1, wc = wid & 1;
  const int m0 = blockIdx.x * BM, n0 = blockIdx.y * BN;

  f32x4 acc[MI][NI] = {};

  for (int k0 = 0; k0 < K; k0 += BK) {
    // ---- stage A tile [BM][BK], linear LDS, source inverse-swizzled ----
    constexpr int IA = BM * BK / (256 * 8);
#pragma unroll
    for (int it = 0; it < IA; ++it) {
      int o = (it * 256 + tid) * 8;       // linear element offset in tile
      int row = o / BK;
      int blk = (o % BK) / 8;             // 16B block index in row
      int col = (blk ^ (row & 7)) * 8;    // inverse swizzle (XOR involution)
      gload_lds16(Amat + (size_t)(m0 + row) * K + k0 + col,
                  Al + (it * 256 + wid * 64) * 8);
    }
    constexpr int IB = BN * BK / (256 * 8);
#pragma unroll
    for (int it = 0; it < IB; ++it) {
      int o = (it * 256 + tid) * 8;
      int row = o / BK;
      int blk = (o % BK) / 8;
      int col = (blk ^ (row & 7)) * 8;
      gload_lds16(Bmat + (size_t)(n0 + row) * K + k0 + col,
                  Bl + (it * 256 + wid * 64) * 8);
    }
    __syncthreads();  // compiler drains vmcnt before s_barrier

#pragma unroll
    for (int kk = 0; kk < BK / 32; ++kk) {
      bf16x8 af[MI], bf[NI];
#pragma unroll
      for (int mi = 0; mi < MI; ++mi) {
        int row = wr * WM + mi * 16 + l15;
        int blk = (kk * 4 + lhi) ^ (row & 7);
        af[mi] = *(const bf16x8*)((const char*)Al + row * (BK * 2) + blk * 16);
      }
#pragma unroll
      for (int ni = 0; ni < NI; ++ni) {
        int row = wc * WN + ni * 16 + l15;
        int blk = (kk * 4 + lhi) ^ (row & 7);
        bf[ni] = *(const bf16x8*)((const char*)Bl + row * (BK * 2) + blk * 16);
      }
#pragma unroll
      for (int mi = 0; mi < MI; ++mi)
#pragma unroll
        for (int ni = 0; ni < NI; ++ni)
          acc[mi][ni] = __builtin_amdgcn_mfma_f32_16x16x32_bf16(af[mi], bf[ni],
                                                                acc[mi][ni], 0, 0, 0);
    }
    __syncthreads();
  }

  // ---- epilogue: C/D layout col=lane&15, row=(lane>>4)*4+reg ----
#pragma unroll
  for (int ni = 0; ni < NI; ++ni) {
    int col = n0 + wc * WN + ni * 16 + l15;
    float bv = 0.f;
    if constexpr (BIAS) bv = bias[col];
#pragma unroll
    for (int mi = 0; mi < MI; ++mi) {
#pragma unroll
      for (int r = 0; r < 4; ++r) {
        int row = m0 + wr * WM + mi * 16 + lhi * 4 + r;
        if constexpr (OUT_F32)
          ((float*)Cout)[(size_t)row * N + col] = acc[mi][ni][r] + bv;
        else
          ((__bf16*)Cout)[(size_t)row * N + col] = (__bf16)acc[mi][ni][r];
      }
    }
  }
}

extern "C" void kernel_launch(void* const* d_in, const int* in_sizes, int n_in,
                              void* d_out, int out_size, void* d_ws, size_t ws_size,
                              hipStream_t stream) {
  const float* x    = (const float*)d_in[0];
  const float* A    = (const float*)d_in[1];
  const float* B    = (const float*)d_in[2];
  const float* bias = (const float*)d_in[3];
  float* out = (float*)d_out;

  // x_bf16 lives in the front 64 MiB of d_out (128 MiB f32 output buffer).
  // It is fully consumed by GEMM1 before GEMM2 overwrites d_out.
  __bf16* xb = (__bf16*)d_out;
  char* ws = (char*)d_ws;
  __bf16* Ab = (__bf16*)ws;                        // [D_OUT][RANK] bf16, 4 MiB
  __bf16* Bt = (__bf16*)(ws + ((size_t)4 << 20));  // [RANK][D_IN]  bf16, 4 MiB
  __bf16* Tt = (__bf16*)(ws + ((size_t)8 << 20));  // [MROWS][RANK] bf16, 8 MiB

  hipLaunchKernelGGL(cvt_f32_bf16, dim3(2048), dim3(256), 0, stream,
                     x, xb, (size_t)MROWS * D_IN);
  hipLaunchKernelGGL(cvt_f32_bf16, dim3(512), dim3(256), 0, stream,
                     A, Ab, (size_t)D_OUT * RANK);
  hipLaunchKernelGGL(transpose_cvt, dim3(D_IN / 64, RANK / 64), dim3(256), 0, stream,
                     B, Bt, D_IN, RANK);
  // t = x @ B   (Bt is [RANK][D_IN] = B^T, i.e. [N,K] layout)
  hipLaunchKernelGGL((gemm_bt<128, 64, 64, false, false>),
                     dim3(MROWS / 128, RANK / 64), dim3(256), 0, stream,
                     xb, Bt, nullptr, Tt, MROWS, RANK, D_IN);
  // out = t @ A^T + bias   (Ab is [D_OUT][RANK] = [N,K] layout)
  hipLaunchKernelGGL((gemm_bt<128, 128, 64, true, true>),
                     dim3(MROWS / 128, D_OUT / 128), dim3(256), 0, stream,
                     Tt, Ab, bias, out, MROWS, D_OUT, RANK);
}